// Round 1
// 556.293 us; speedup vs baseline: 1.0402x; 1.0402x over previous
//
#include <hip/hip_runtime.h>
#include <hip/hip_bf16.h>

typedef __bf16 bf16;
typedef __bf16 bf16x8 __attribute__((ext_vector_type(8)));
typedef float  f32x4  __attribute__((ext_vector_type(4)));

#define S_SP 3136              // 56*56
#define SCALE_V (1.0f/896.0f)  // (56*56*256)^-0.5, exact (896^2 = 802816)

__device__ __forceinline__ float bf2f(bf16 x) { return (float)x; }

// load 8 consecutive elements as bf16x8 (f32 source converts)
__device__ __forceinline__ bf16x8 load8(const float* p) {
    f32x4 a = *(const f32x4*)p;
    f32x4 b = *(const f32x4*)(p + 4);
    bf16x8 r;
    r[0] = (bf16)a[0]; r[1] = (bf16)a[1]; r[2] = (bf16)a[2]; r[3] = (bf16)a[3];
    r[4] = (bf16)b[0]; r[5] = (bf16)b[1]; r[6] = (bf16)b[2]; r[7] = (bf16)b[3];
    return r;
}
__device__ __forceinline__ bf16x8 load8(const bf16* p) { return *(const bf16x8*)p; }

// ---------------------------------------------------------------------------
// conv1x1 as GEMM: Y[b,o,s] = epilogue( sum_c W[o,c] * X[b,c,s] )
// block = 256 threads (4 waves); tile M=64 (o) x N=64 (s); K-step 32.
// grid: (49, O/64, 16)
// ---------------------------------------------------------------------------
template<typename TX, typename TY, int CIN, bool LRELU, bool PAD_OUT>
__global__ __launch_bounds__(256)
void conv1x1_kernel(const TX* __restrict__ X, const float* __restrict__ W,
                    const float* __restrict__ bias, const float* __restrict__ bng,
                    const float* __restrict__ bnb, TY* __restrict__ Y, int O)
{
    __shared__ bf16 Xt[64][72];   // [s_local][c_local 0..31]
    const int s0  = blockIdx.x * 64;
    const int o0  = blockIdx.y * 64;
    const int b   = blockIdx.z;
    const int tid = threadIdx.x;
    const int wv = tid >> 6, lane = tid & 63, li = lane & 15, quad = lane >> 4;

    const TX* Xb = X + (size_t)b * CIN * S_SP;

    f32x4 acc[4];
    #pragma unroll
    for (int nt = 0; nt < 4; ++nt) acc[nt] = f32x4{0.f, 0.f, 0.f, 0.f};

    #pragma unroll
    for (int k0 = 0; k0 < CIN; k0 += 32) {
        if (k0) __syncthreads();
        {   // stage X[k0+cl][s0+sj..+8) -> Xt[sj..][cl]
            int cl = tid >> 3;
            int sj = (tid & 7) * 8;
            bf16x8 v = load8(Xb + (size_t)(k0 + cl) * S_SP + s0 + sj);
            #pragma unroll
            for (int u = 0; u < 8; ++u) Xt[sj + u][cl] = v[u];
        }
        __syncthreads();
        bf16x8 a = load8(W + (size_t)(o0 + wv * 16 + li) * CIN + k0 + quad * 8);
        #pragma unroll
        for (int nt = 0; nt < 4; ++nt) {
            bf16x8 bb = *(const bf16x8*)&Xt[nt * 16 + li][quad * 8];
            acc[nt] = __builtin_amdgcn_mfma_f32_16x16x32_bf16(a, bb, acc[nt], 0, 0, 0);
        }
    }

    const float rs = rsqrtf(1.0f + 1e-5f);
    #pragma unroll
    for (int r = 0; r < 4; ++r) {
        int o = o0 + wv * 16 + quad * 4 + r;
        float bi = bias ? bias[o] : 0.f;
        float sc = bng ? bng[o] * rs : 1.f;
        float sh = bnb ? bnb[o] : 0.f;
        #pragma unroll
        for (int nt = 0; nt < 4; ++nt) {
            float v = acc[nt][r] + bi;
            v = v * sc + sh;
            if (LRELU) v = (v >= 0.f) ? v : 0.2f * v;
            int s = s0 + nt * 16 + li;
            if (!PAD_OUT) {
                Y[((size_t)b * O + o) * S_SP + s] = (TY)v;
            } else {
                int rr = s / 56, cc = s % 56;
                Y[(((size_t)b * O + o) * 58 + rr + 1) * 58 + cc + 1] = (TY)v;
            }
        }
    }
}

// ---------------------------------------------------------------------------
// FUSED attention per (b,c):
//   phase 1 (local):  S = Q K^T (pad 56->64), row softmax, oacc = P V
//   phase 2 (global): P_g[h][k] = softmax_k(gs * GK[h][k]), oacc += P_g GV
//   write F = oacc once (no F read-modify-write).
// GK/GV are prefetched into registers during phase 1 so their HBM/L2 latency
// hides under the local MFMAs. grid 4096 x 256.
// ---------------------------------------------------------------------------
__global__ __launch_bounds__(256)
void attn_kernel(const bf16* __restrict__ Q, const bf16* __restrict__ K,
                 const bf16* __restrict__ V, const float* __restrict__ gq,
                 const bf16* __restrict__ GK, const bf16* __restrict__ GV,
                 bf16* __restrict__ F)
{
    __shared__ bf16 Qs[64][72], Ks[64][72], Vt[64][72], Ps[64][72];
    const int bc  = blockIdx.x;
    const int tid = threadIdx.x;
    const int wv = tid >> 6, lane = tid & 63, li = lane & 15, quad = lane >> 4;
    const int m0 = wv * 16;

    #pragma unroll
    for (int i = tid; i < 64 * 36; i += 256) {
        ((uint32_t*)Qs)[i] = 0; ((uint32_t*)Ks)[i] = 0;
        ((uint32_t*)Vt)[i] = 0; ((uint32_t*)Ps)[i] = 0;
    }
    __syncthreads();

    const bf16* Qp = Q + (size_t)bc * S_SP;
    const bf16* Kp = K + (size_t)bc * S_SP;
    const bf16* Vp = V + (size_t)bc * S_SP;
    for (int idx = tid; idx < 392; idx += 256) {   // 56 rows * 7 chunks of 8
        int r = idx / 7, cj = (idx % 7) * 8;
        *(bf16x8*)&Qs[r][cj] = *(const bf16x8*)(Qp + r * 56 + cj);
        *(bf16x8*)&Ks[r][cj] = *(const bf16x8*)(Kp + r * 56 + cj);
        bf16x8 vv = *(const bf16x8*)(Vp + r * 56 + cj);
        #pragma unroll
        for (int u = 0; u < 8; ++u) Vt[cj + u][r] = vv[u];  // Vt[w][v]
    }

    // ---- phase-2 prefetch: GV chunks (written to LDS after local PV) ----
    const float gs = gq[bc];
    const bf16* GVp = GV + (size_t)bc * S_SP;
    const bf16* GKp = GK + (size_t)bc * S_SP;
    const int ra  = tid / 7,            cja = (tid % 7) * 8;
    const bool hasb = tid < 136;        // idx = tid + 256 < 392
    const int rb  = (tid + 256) / 7,    cjb = ((tid + 256) % 7) * 8;
    bf16x8 gva = *(const bf16x8*)(GVp + ra * 56 + cja);
    bf16x8 gvb = hasb ? *(const bf16x8*)(GVp + rb * 56 + cjb) : bf16x8{};
    __syncthreads();

    // S = Q K^T : A[m=h][k=w]=Qs[h][w], B[k=w][n=v]=Ks[v][w]
    f32x4 sacc[4];
    #pragma unroll
    for (int nt = 0; nt < 4; ++nt) sacc[nt] = f32x4{0.f, 0.f, 0.f, 0.f};
    #pragma unroll
    for (int k0 = 0; k0 < 64; k0 += 32) {
        bf16x8 a = *(const bf16x8*)&Qs[m0 + li][k0 + quad * 8];
        #pragma unroll
        for (int nt = 0; nt < 4; ++nt) {
            bf16x8 bb = *(const bf16x8*)&Ks[nt * 16 + li][k0 + quad * 8];
            sacc[nt] = __builtin_amdgcn_mfma_f32_16x16x32_bf16(a, bb, sacc[nt], 0, 0, 0);
        }
    }

    // local row softmax: row = m0+quad*4+r, cols spread over (nt regs, li lanes)
    #pragma unroll
    for (int r = 0; r < 4; ++r) {
        float e[4]; float m = -3e38f;
        #pragma unroll
        for (int nt = 0; nt < 4; ++nt) {
            int v = nt * 16 + li;
            float x = (v < 56) ? sacc[nt][r] * SCALE_V : -3e38f;
            e[nt] = x; m = fmaxf(m, x);
        }
        m = fmaxf(m, __shfl_xor(m, 1)); m = fmaxf(m, __shfl_xor(m, 2));
        m = fmaxf(m, __shfl_xor(m, 4)); m = fmaxf(m, __shfl_xor(m, 8));
        float s = 0.f;
        #pragma unroll
        for (int nt = 0; nt < 4; ++nt) {
            float p = (nt * 16 + li < 56) ? __expf(e[nt] - m) : 0.f;
            e[nt] = p; s += p;
        }
        s += __shfl_xor(s, 1); s += __shfl_xor(s, 2);
        s += __shfl_xor(s, 4); s += __shfl_xor(s, 8);
        float inv = 1.f / s;
        int row = m0 + quad * 4 + r;
        #pragma unroll
        for (int nt = 0; nt < 4; ++nt) Ps[row][nt * 16 + li] = (bf16)(e[nt] * inv);
    }

    // ---- phase-2 prefetch: GK values for the global softmax (overlaps PV) ----
    float gkv[4][4];
    #pragma unroll
    for (int r = 0; r < 4; ++r) {
        int row = m0 + quad * 4 + r;
        int hrow = (row < 56) ? row : 0;            // rows >=56 discarded later
        #pragma unroll
        for (int nt = 0; nt < 4; ++nt) {
            int v = nt * 16 + li;
            gkv[r][nt] = (v < 56) ? bf2f(GKp[hrow * 56 + v]) : 0.f;
        }
    }
    __syncthreads();

    // oacc = P V : A[m=h][k=v]=Ps[h][v], B[k=v][n=w]=Vt[w][v]
    f32x4 oacc[4];
    #pragma unroll
    for (int nt = 0; nt < 4; ++nt) oacc[nt] = f32x4{0.f, 0.f, 0.f, 0.f};
    #pragma unroll
    for (int k0 = 0; k0 < 64; k0 += 32) {
        bf16x8 a = *(const bf16x8*)&Ps[m0 + li][k0 + quad * 8];
        #pragma unroll
        for (int nt = 0; nt < 4; ++nt) {
            bf16x8 bb = *(const bf16x8*)&Vt[nt * 16 + li][k0 + quad * 8];
            oacc[nt] = __builtin_amdgcn_mfma_f32_16x16x32_bf16(a, bb, oacc[nt], 0, 0, 0);
        }
    }

    // ---- phase 2: global attention, accumulate into oacc ----
    __syncthreads();   // local PV reads of Ps/Vt done; safe to overwrite

    // GV transpose into Vt (pad region still zero from init)
    #pragma unroll
    for (int u = 0; u < 8; ++u) Vt[cja + u][ra] = gva[u];
    if (hasb) {
        #pragma unroll
        for (int u = 0; u < 8; ++u) Vt[cjb + u][rb] = gvb[u];
    }

    // global row softmax (wave-parallel, same layout as local)
    #pragma unroll
    for (int r = 0; r < 4; ++r) {
        float e[4]; float m = -3e38f;
        #pragma unroll
        for (int nt = 0; nt < 4; ++nt) {
            int v = nt * 16 + li;
            float x = (v < 56) ? gs * gkv[r][nt] : -3e38f;
            e[nt] = x; m = fmaxf(m, x);
        }
        m = fmaxf(m, __shfl_xor(m, 1)); m = fmaxf(m, __shfl_xor(m, 2));
        m = fmaxf(m, __shfl_xor(m, 4)); m = fmaxf(m, __shfl_xor(m, 8));
        float s = 0.f;
        #pragma unroll
        for (int nt = 0; nt < 4; ++nt) {
            float p = (nt * 16 + li < 56) ? __expf(e[nt] - m) : 0.f;
            e[nt] = p; s += p;
        }
        s += __shfl_xor(s, 1); s += __shfl_xor(s, 2);
        s += __shfl_xor(s, 4); s += __shfl_xor(s, 8);
        float inv = 1.f / s;
        int row = m0 + quad * 4 + r;
        #pragma unroll
        for (int nt = 0; nt < 4; ++nt) Ps[row][nt * 16 + li] = (bf16)(e[nt] * inv);
    }
    __syncthreads();

    // oacc += P_g GV
    #pragma unroll
    for (int k0 = 0; k0 < 64; k0 += 32) {
        bf16x8 a = *(const bf16x8*)&Ps[m0 + li][k0 + quad * 8];
        #pragma unroll
        for (int nt = 0; nt < 4; ++nt) {
            bf16x8 bb = *(const bf16x8*)&Vt[nt * 16 + li][k0 + quad * 8];
            oacc[nt] = __builtin_amdgcn_mfma_f32_16x16x32_bf16(a, bb, oacc[nt], 0, 0, 0);
        }
    }

    bf16* Fp = F + (size_t)bc * S_SP;
    #pragma unroll
    for (int r = 0; r < 4; ++r) {
        int h = m0 + quad * 4 + r;
        #pragma unroll
        for (int nt = 0; nt < 4; ++nt) {
            int w = nt * 16 + li;
            if (h < 56 && w < 56) Fp[h * 56 + w] = (bf16)oacc[nt][r];
        }
    }
}

// ---------------------------------------------------------------------------
__global__ __launch_bounds__(256)
void spatial_mean_kernel(const float* __restrict__ X, float* __restrict__ out)
{
    int bc = blockIdx.x, tid = threadIdx.x;
    const float* p = X + (size_t)bc * S_SP;
    float s = 0.f;
    for (int i = tid; i < S_SP; i += 256) s += p[i];
    for (int off = 32; off; off >>= 1) s += __shfl_down(s, off, 64);
    __shared__ float ws[4];
    if ((tid & 63) == 0) ws[tid >> 6] = s;
    __syncthreads();
    if (tid == 0) out[bc] = (ws[0] + ws[1] + ws[2] + ws[3]) * (1.0f / S_SP);
}

// Tiny global-branch MLP: grid 16 (per batch), 256 threads.
__global__ __launch_bounds__(256)
void gq_kernel(const float* __restrict__ pmean,
               const float* c11w, const float* c11b,
               const float* gaw1, const float* gab1, const float* gag1, const float* gabe1,
               const float* gaw2, const float* gab2, const float* gag2, const float* gabe2,
               float* __restrict__ gq)
{
    __shared__ float pm[256], p2[256], hh[64];
    int b = blockIdx.x, t = threadIdx.x;
    pm[t] = pmean[b * 256 + t];
    __syncthreads();
    float a = c11b[t];
    for (int c = 0; c < 256; ++c) a += c11w[t * 256 + c] * pm[c];
    p2[t] = a;
    __syncthreads();
    const float rs = rsqrtf(1.0f + 1e-5f);
    if (t < 64) {
        float h = gab1[t];
        for (int c = 0; c < 256; ++c) h += gaw1[t * 256 + c] * p2[c];
        h = h * (gag1[t] * rs) + gabe1[t];
        hh[t] = (h >= 0.f) ? h : 0.2f * h;
    }
    __syncthreads();
    float g = gab2[t];
    for (int i = 0; i < 64; ++i) g += gaw2[t * 64 + i] * hh[i];
    g = g * (gag2[t] * rs) + gabe2[t];
    gq[b * 256 + t] = g * SCALE_V;  // attention SCALE folded in
}

// Border-only fill: 228 border elems per 58x58 image (interior written by conv).
// grid = 16*256*228/256 = 3648 blocks exactly.
__global__ __launch_bounds__(256)
void fill_border_kernel(float* __restrict__ out, const float* __restrict__ c1b)
{
    int idx = blockIdx.x * 256 + threadIdx.x;
    int e  = idx % 228;
    int bo = idx / 228;
    if (bo >= 16 * 256) return;
    int o = bo & 255;
    int r, c;
    if (e < 58)       { r = 0;  c = e; }
    else if (e < 116) { r = 57; c = e - 58; }
    else { int t = e - 116; r = 1 + (t >> 1); c = (t & 1) * 57; }
    out[(size_t)bo * 3364 + r * 58 + c] = c1b[o];
}

// ---------------------------------------------------------------------------
extern "C" void kernel_launch(void* const* d_in, const int* in_sizes, int n_in,
                              void* d_out, int out_size, void* d_ws, size_t ws_size,
                              hipStream_t stream)
{
    (void)in_sizes; (void)n_in; (void)out_size; (void)ws_size;
    const float* x_s   = (const float*)d_in[0];
    const float* x_fq  = (const float*)d_in[1];
    const float* x_mt  = (const float*)d_in[2];
    const float* la_w1 = (const float*)d_in[3];
    const float* la_b1 = (const float*)d_in[4];
    const float* la_g1 = (const float*)d_in[5];
    const float* la_be1= (const float*)d_in[6];
    const float* la_w2 = (const float*)d_in[7];
    const float* la_b2 = (const float*)d_in[8];
    const float* la_g2 = (const float*)d_in[9];
    const float* la_be2= (const float*)d_in[10];
    const float* lk_w  = (const float*)d_in[11];
    const float* lk_b  = (const float*)d_in[12];
    const float* lv_w  = (const float*)d_in[13];
    const float* ga_w1 = (const float*)d_in[14];
    const float* ga_b1 = (const float*)d_in[15];
    const float* ga_g1 = (const float*)d_in[16];
    const float* ga_be1= (const float*)d_in[17];
    const float* ga_w2 = (const float*)d_in[18];
    const float* ga_b2 = (const float*)d_in[19];
    const float* ga_g2 = (const float*)d_in[20];
    const float* ga_be2= (const float*)d_in[21];
    const float* gk_w  = (const float*)d_in[22];
    const float* gk_b  = (const float*)d_in[23];
    const float* gv_w  = (const float*)d_in[24];
    const float* c11_w = (const float*)d_in[25];
    const float* c11_b = (const float*)d_in[26];
    const float* c1_w  = (const float*)d_in[27];
    const float* c1_b  = (const float*)d_in[28];
    float* out = (float*)d_out;

    char* ws = (char*)d_ws;
    const size_t SZ = (size_t)16 * 256 * S_SP * 2;       // 25,690,112 B (bf16)
    bf16* Q  = (bf16*)(ws);                              // aliased as F below
    bf16* K  = (bf16*)(ws + SZ);
    bf16* V  = (bf16*)(ws + 2 * SZ);
    bf16* GK = (bf16*)(ws + 3 * SZ);
    bf16* GV = (bf16*)(ws + 4 * SZ);
    bf16* Hd = (bf16*)(ws + 5 * SZ);                     // 16*64*3136 bf16
    float* pmean = (float*)(ws + 5 * SZ + (size_t)16 * 64 * S_SP * 2);
    float* gq    = pmean + 16 * 256;
    bf16* F  = Q;  // safe alias: each attn block reads only its own bc slice of Q
                   // (staged before any write) and writes only its own bc slice of F

    dim3 blk(256);
    // output border only (interior fully written by final conv)
    fill_border_kernel<<<dim3(3648), blk, 0, stream>>>(out, c1_b);

    // ---- local branch projections ----
    conv1x1_kernel<float, bf16, 256, true,  false><<<dim3(49, 1, 16), blk, 0, stream>>>(
        x_s, la_w1, la_b1, la_g1, la_be1, Hd, 64);
    conv1x1_kernel<bf16, bf16, 64,  false, false><<<dim3(49, 4, 16), blk, 0, stream>>>(
        Hd, la_w2, la_b2, la_g2, la_be2, Q, 256);
    conv1x1_kernel<float, bf16, 256, false, false><<<dim3(49, 4, 16), blk, 0, stream>>>(
        x_s, lk_w, lk_b, nullptr, nullptr, K, 256);
    conv1x1_kernel<float, bf16, 256, false, false><<<dim3(49, 4, 16), blk, 0, stream>>>(
        x_s, lv_w, nullptr, nullptr, nullptr, V, 256);

    // ---- global branch projections ----
    spatial_mean_kernel<<<dim3(4096), blk, 0, stream>>>(x_mt, pmean);
    gq_kernel<<<dim3(16), blk, 0, stream>>>(pmean, c11_w, c11_b,
        ga_w1, ga_b1, ga_g1, ga_be1, ga_w2, ga_b2, ga_g2, ga_be2, gq);
    conv1x1_kernel<float, bf16, 256, false, false><<<dim3(49, 4, 16), blk, 0, stream>>>(
        x_fq, gk_w, gk_b, nullptr, nullptr, GK, 256);
    conv1x1_kernel<float, bf16, 256, false, false><<<dim3(49, 4, 16), blk, 0, stream>>>(
        x_fq, gv_w, nullptr, nullptr, nullptr, GV, 256);

    // ---- fused local+global attention, writes F once ----
    attn_kernel<<<dim3(4096), blk, 0, stream>>>(Q, K, V, gq, GK, GV, F);

    // ---- output conv (writes interior of padded 58x58) ----
    conv1x1_kernel<bf16, float, 256, false, true><<<dim3(49, 4, 16), blk, 0, stream>>>(
        F, c1_w, c1_b, nullptr, nullptr, out, 256);
}